// Round 4
// baseline (50.838 us; speedup 1.0000x reference)
//
#include <hip/hip_runtime.h>
#include <hip/hip_bf16.h>

// ---------------------------------------------------------------------------
// Metric_Loss: two fused (X X^T/128 -> exp(1+.) -> row-sum) passes + pair combine.
// B=8192, E=128, P=4096.  Output: scalar f32 = metric_tt + metric_st.
//
// Round 4: occupancy restructure. 64-row strips (128 of them), 64x64 tiles,
// 4 waves/block each computing a 32x32 quadrant. LDS = 2 x 16KB buffers,
// regs <= 128 -> 4 blocks/CU resident, 16 waves/CU, 4 waves/SIMD (vs 2).
// Same symmetric wrap-pairing + 2-phase counted-vmcnt pipeline as R3.
//
// ws layout:
//   [0, 2MB)        Xt bf16   [8192][128]   scaled by sqrt(log2e/128)
//   [2MB, 4MB)      Xm bf16   [8192][128]   (mixed: even=text, odd=shape[r>>1])
//   [4MB, 4MB+64KB) R f32     [2][8192]     row sums of exp(1+D)
// ---------------------------------------------------------------------------

#define B_ROWS 8192
#define E_COLS 128
#define P_PAIRS 4096
#define NSTRIP 128              // 64-row strips

using short8 = __attribute__((ext_vector_type(8))) short;
using f32x4  = __attribute__((ext_vector_type(4))) float;

// sqrt(log2(e)/128): MFMA yields acc = D*log2(e); exp(1+D) = e * exp2(acc)
#define BF_SCALE 0.106164482742544f
#define EULER    2.718281828459045f

__device__ __forceinline__ unsigned short f2bf(float f) {
    unsigned u = __builtin_bit_cast(unsigned, f);
    unsigned r = (u + 0x7fffu + ((u >> 16) & 1u)) >> 16;   // RNE
    return (unsigned short)r;
}

// --------------------------- conversion kernel -----------------------------
__global__ void convert_kernel(const float* __restrict__ text,
                               const float* __restrict__ shape,
                               unsigned short* __restrict__ Xt,
                               unsigned short* __restrict__ Xm,
                               float* __restrict__ R,
                               float* __restrict__ out) {
    int idx = blockIdx.x * blockDim.x + threadIdx.x;     // one float4 per thread
    if (idx < 4096) {                                    // zero R (2*8192 f32)
        float4 z; z.x = z.y = z.z = z.w = 0.f;
        ((float4*)R)[idx] = z;
    }
    if (idx == 0) *out = 0.f;
    int e = idx * 4;
    if (e >= B_ROWS * E_COLS) return;
    float4 t = *(const float4*)(text + e);
    ushort4 tb;
    tb.x = f2bf(t.x * BF_SCALE); tb.y = f2bf(t.y * BF_SCALE);
    tb.z = f2bf(t.z * BF_SCALE); tb.w = f2bf(t.w * BF_SCALE);
    *(ushort4*)(Xt + e) = tb;
    int row = e >> 7;
    if (row & 1) {
        int col = e & 127;
        float4 s = *(const float4*)(shape + (row >> 1) * E_COLS + col);
        ushort4 sb;
        sb.x = f2bf(s.x * BF_SCALE); sb.y = f2bf(s.y * BF_SCALE);
        sb.z = f2bf(s.z * BF_SCALE); sb.w = f2bf(s.w * BF_SCALE);
        *(ushort4*)(Xm + e) = sb;
    } else {
        *(ushort4*)(Xm + e) = tb;
    }
}

// --------------------------- fused GEMM + rowsum ---------------------------
__device__ __forceinline__ int swz(int row, int cb) {
    return (row << 8) + (cb ^ ((row & 7) << 4));
}

// Stage one 64x128 bf16 tile (16KB): linear LDS dest, pre-swizzled global src.
__device__ __forceinline__ void stage16k(const char* gsrc, char* ldst, int tid) {
#pragma unroll
    for (int it = 0; it < 4; ++it) {
        int L   = it * 4096 + tid * 16;
        int row = L >> 8;
        int cb  = L & 255;
        int src = (row << 8) + (cb ^ ((row & 7) << 4));
        __builtin_amdgcn_global_load_lds(
            (const __attribute__((address_space(1))) void*)(gsrc + src),
            (__attribute__((address_space(3))) void*)(ldst + L), 16, 0, 0);
    }
}

// Block = (strip bm in 0..127, split h in 0..3, layer l). Strip = 64 A-rows.
// Tiles (bm, bn=(bm+t)&127): t in {1..63} each unordered pair once; t==64
// gated bm<64; t==0 diagonal (h==0 only, computed in prologue from buf0).
__launch_bounds__(256, 4)
__global__ void gemm_rowsum_kernel(const unsigned short* __restrict__ Xt,
                                   const unsigned short* __restrict__ Xm,
                                   float* __restrict__ R) {
    const int bm = blockIdx.x, h = blockIdx.y, l = blockIdx.z;
    const unsigned short* X = l ? Xm : Xt;

    __shared__ __align__(16) unsigned short buf0[64 * 128];
    __shared__ __align__(16) unsigned short buf1[64 * 128];
    const int tid = threadIdx.x;
    char* lb0 = (char*)buf0;
    char* lb1 = (char*)buf1;
    const char* gX = (const char*)X;

    const int t0 = (h == 0) ? 4 : h;
    const int N  = (h == 0) ? (bm < 64 ? 16 : 15) : 16;   // off-diag tile count

    // ---- prologue: stage A -> buf0, first B -> buf1 (both in flight) ----
    stage16k(gX + bm * 16384, lb0, tid);
    stage16k(gX + ((bm + t0) & 127) * 16384, lb1, tid);
    asm volatile("s_waitcnt vmcnt(4)" ::: "memory");       // A landed
    __builtin_amdgcn_s_barrier();

    const int lane = tid & 63;
    const int w  = tid >> 6;
    const int wr = w >> 1, wc = w & 1;
    const int rA0 = wr * 32 + (lane & 15);
    const int rB0 = wc * 32 + (lane & 15);
    const int kb  = (lane >> 4) * 16;            // byte offset of lane's k-slice

    // ---- hoist A fragments (2 m-frags x 4 kk) ----
    short8 afr[4][2];
#pragma unroll
    for (int kk = 0; kk < 4; ++kk)
#pragma unroll
        for (int m = 0; m < 2; ++m)
            afr[kk][m] = *(const short8*)(lb0 + swz(rA0 + m * 16, kk * 64 + kb));

    float s_r[2][4] = {{0.f}};                   // persistent row partials [m][j]

    // ---- diagonal tile (h==0): B-frags also from buf0; rows only ----
    if (h == 0) {
        f32x4 acc[2][2] = {};
#pragma unroll
        for (int kk = 0; kk < 4; ++kk) {
            short8 bfr[2];
#pragma unroll
            for (int n = 0; n < 2; ++n)
                bfr[n] = *(const short8*)(lb0 + swz(rB0 + n * 16, kk * 64 + kb));
#pragma unroll
            for (int m = 0; m < 2; ++m)
#pragma unroll
                for (int n = 0; n < 2; ++n)
                    acc[m][n] = __builtin_amdgcn_mfma_f32_16x16x32_bf16(
                        afr[kk][m], bfr[n], acc[m][n], 0, 0, 0);
        }
#pragma unroll
        for (int m = 0; m < 2; ++m)
#pragma unroll
            for (int n = 0; n < 2; ++n)
#pragma unroll
                for (int j = 0; j < 4; ++j)
                    s_r[m][j] += __builtin_amdgcn_exp2f(acc[m][n][j]);
    }

    // ---- all buf0 reads done before it becomes a B buffer ----
    asm volatile("s_waitcnt lgkmcnt(0)" ::: "memory");
    __builtin_amdgcn_s_barrier();

    // ---- 2-phase pipelined loop over off-diagonal tiles ----
    int cur = 1;                                 // current B buffer: 1 -> buf1
    for (int idx = 0; idx < N; ++idx) {
        const bool hasnext = (idx + 1 < N);
        if (hasnext)
            stage16k(gX + ((bm + t0 + 4 * (idx + 1)) & 127) * 16384,
                     cur ? lb0 : lb1, tid);

        if (hasnext) { asm volatile("s_waitcnt vmcnt(4)" ::: "memory"); }
        else         { asm volatile("s_waitcnt vmcnt(0)" ::: "memory"); }
        __builtin_amdgcn_s_barrier();            // cur buffer staged (all waves)

        const char* lsrc = cur ? lb1 : lb0;
        f32x4 acc[2][2] = {};
#pragma unroll
        for (int kk = 0; kk < 4; ++kk) {
            short8 bfr[2];
#pragma unroll
            for (int n = 0; n < 2; ++n)
                bfr[n] = *(const short8*)(lsrc + swz(rB0 + n * 16, kk * 64 + kb));
#pragma unroll
            for (int m = 0; m < 2; ++m)
#pragma unroll
                for (int n = 0; n < 2; ++n)
                    acc[m][n] = __builtin_amdgcn_mfma_f32_16x16x32_bf16(
                        afr[kk][m], bfr[n], acc[m][n], 0, 0, 0);
        }

        asm volatile("s_waitcnt lgkmcnt(0)" ::: "memory");
        __builtin_amdgcn_s_barrier();            // cur reads done -> overwritable

        // ---- epilogue: rows -> regs, cols -> shuffle + atomics ----
        const int bn = (bm + t0 + 4 * idx) & 127;
        float s_c[2] = {0.f, 0.f};
#pragma unroll
        for (int m = 0; m < 2; ++m)
#pragma unroll
            for (int n = 0; n < 2; ++n)
#pragma unroll
                for (int j = 0; j < 4; ++j) {
                    float e2 = __builtin_amdgcn_exp2f(acc[m][n][j]);
                    s_r[m][j] += e2;
                    s_c[n] += e2;
                }
#pragma unroll
        for (int n = 0; n < 2; ++n) {
            float v = s_c[n];
            v += __shfl_xor(v, 16, 64);
            v += __shfl_xor(v, 32, 64);
            if (lane < 16) {
                int gcol = bn * 64 + wc * 32 + n * 16 + lane;
                atomicAdd(&R[l * B_ROWS + gcol], EULER * v);
            }
        }
        cur ^= 1;
    }

    // ---- final row reduction (once per block) ----
#pragma unroll
    for (int m = 0; m < 2; ++m)
#pragma unroll
        for (int j = 0; j < 4; ++j) {
            float v = s_r[m][j];
            v += __shfl_xor(v, 1, 64);
            v += __shfl_xor(v, 2, 64);
            v += __shfl_xor(v, 4, 64);
            v += __shfl_xor(v, 8, 64);
            if ((lane & 15) == 0) {
                int grow = bm * 64 + wr * 32 + m * 16 + (lane >> 4) * 4 + j;
                atomicAdd(&R[l * B_ROWS + grow], EULER * v);
            }
        }
}

// --------------------------- finalize --------------------------------------
__global__ void finalize_kernel(const float* __restrict__ text,
                                const float* __restrict__ shape,
                                const float* __restrict__ R,
                                float* __restrict__ out) {
    const int tid = threadIdx.x;
    const int lane = tid & 63;
    const int w = tid >> 6;
    const int waveGlobal = blockIdx.x * 4 + w;   // 1024 waves total
    const float inv128 = 0.0078125f;
    float accum = 0.f;

    for (int task = waveGlobal; task < 2 * P_PAIRS; task += 1024) {
        int l = task >> 12;
        int p = task & (P_PAIRS - 1);
        const float* a = text + (2 * p) * E_COLS;                       // even row: always text
        const float* b = l ? (shape + p * E_COLS) : (text + (2 * p + 1) * E_COLS);
        float2 av = *(const float2*)(a + lane * 2);
        float2 bv = *(const float2*)(b + lane * 2);
        float dii = av.x * av.x + av.y * av.y;
        float djj = bv.x * bv.x + bv.y * bv.y;
        float dij = av.x * bv.x + av.y * bv.y;
#pragma unroll
        for (int sh = 1; sh < 64; sh <<= 1) {
            dii += __shfl_xor(dii, sh, 64);
            djj += __shfl_xor(djj, sh, 64);
            dij += __shfl_xor(dij, sh, 64);
        }
        if (lane == 0) {
            float Dii = dii * inv128, Djj = djj * inv128, Dij = dij * inv128;
            float S = R[l * B_ROWS + 2 * p] + R[l * B_ROWS + 2 * p + 1]
                    - (__expf(1.f + Dii) + 2.f * __expf(1.f + Dij) + __expf(1.f + Djj));
            float J = __logf(S) - Dij;
            accum += 0.5f * J * J * (1.0f / (float)P_PAIRS);
        }
    }

    __shared__ float red[4];
    if (lane == 0) red[w] = accum;
    __syncthreads();
    if (tid == 0) {
        atomicAdd(out, red[0] + red[1] + red[2] + red[3]);
    }
}

// --------------------------- launch ----------------------------------------
extern "C" void kernel_launch(void* const* d_in, const int* in_sizes, int n_in,
                              void* d_out, int out_size, void* d_ws, size_t ws_size,
                              hipStream_t stream) {
    const float* text  = (const float*)d_in[0];
    const float* shape = (const float*)d_in[1];
    float* out = (float*)d_out;
    char* ws = (char*)d_ws;

    unsigned short* Xt = (unsigned short*)ws;
    unsigned short* Xm = (unsigned short*)(ws + 2u * 1024u * 1024u);
    float* R = (float*)(ws + 4u * 1024u * 1024u);

    convert_kernel<<<(B_ROWS * E_COLS / 4 + 255) / 256, 256, 0, stream>>>(
        text, shape, Xt, Xm, R, out);

    dim3 grid(NSTRIP, 4, 2);                     // 128 strips x 4 splits x 2 layers
    gemm_rowsum_kernel<<<grid, 256, 0, stream>>>(Xt, Xm, R);

    finalize_kernel<<<256, 256, 0, stream>>>(text, shape, R, out);
}